// Round 6
// baseline (155.932 us; speedup 1.0000x reference)
//
#include <hip/hip_runtime.h>
#include <hip/hip_bf16.h>
#include <math.h>

// spatialAttention: B=512, P=128, D=64, domain 12x12, W [64,128], out [512,128,64] f32
#define NB 512
#define NP 128
#define ND 64
#define EPSF 1e-5f
// bf16-element row stride for MFMA-read LDS arrays: 136 elems = 272 B.
#define SW 136

typedef __attribute__((ext_vector_type(8))) short short8;   // 8 bf16 = 4 VGPRs
typedef __attribute__((ext_vector_type(4))) float f32x4;    // MFMA accumulator

// Inline-asm global load: SGPR base + 32-bit unsigned voffset + imm offset.
// Volatile => issue order preserved among asm ops; output "=&v" forces real
// VGPR allocation (R3/R4: plain-C "batched" loads were re-serialized by the
// compiler; VGPR_Count 52/56 proved it).
// RULE (R5 NaN post-mortem): every asm load must be drained by an ASM
// s_waitcnt — the compiler's waitcnt pass does not see asm loads, so
// __syncthreads() does NOT drain them.
#define GLOADX4(dst, voff, base, immstr)                                   \
    asm volatile("global_load_dwordx4 %0, %1, %2 offset:" immstr           \
                 : "=&v"(dst) : "v"(voff), "s"(base))

__device__ __forceinline__ short f2bf(float x) {
    __hip_bfloat16 h = __float2bfloat16(x);
    return *reinterpret_cast<short*>(&h);
}

// bin = floor(x/30) clamped to [0,11]; f64 path matches numpy RN32(x/30).
__device__ __forceinline__ int bin30(float x) {
    float t = (float)((double)x * (1.0 / 30.0));
    int i = (int)t;
    return i < 0 ? 0 : (i > 11 ? 11 : i);
}

__device__ __forceinline__ float fast_tanh(float x) {
    float e = __expf(2.0f * x);
    return 1.0f - 2.0f * __builtin_amdgcn_rcpf(e + 1.0f);
}

// W as bf16 [64][128], produced by prep kernel each launch (graph-safe).
__device__ __align__(16) short g_wbf[ND * 2 * ND];

__global__ __launch_bounds__(256) void prep_w(const float* __restrict__ W) {
    int idx = blockIdx.x * 256 + threadIdx.x;     // 2048 float4
    float4 v = ((const float4*)W)[idx];
    short4 s4;
    s4.x = f2bf(v.x); s4.y = f2bf(v.y); s4.z = f2bf(v.z); s4.w = f2bf(v.w);
    *(short4*)&g_wbf[idx * 4] = s4;
}

// 8 E values (cols c0..c0+7 of row p) in bf16, MFMA A-fragment packed.
__device__ __forceinline__ short8 calc_e8(
    float4 d0, float4 d1, float4 b0, float4 b1, float4 h0, float4 h1,
    float4 m0, float4 m1, const float* s_dom, float mp, int c0, int p)
{
    float dv[8] = {d0.x, d0.y, d0.z, d0.w, d1.x, d1.y, d1.z, d1.w};
    float bv[8] = {b0.x, b0.y, b0.z, b0.w, b1.x, b1.y, b1.z, b1.w};
    float hv[8] = {h0.x, h0.y, h0.z, h0.w, h1.x, h1.y, h1.z, h1.w};
    float mv[8] = {m0.x, m0.y, m0.z, m0.w, m1.x, m1.y, m1.z, m1.w};
    short8 a;
    #pragma unroll
    for (int j = 0; j < 8; ++j) {
        int i1 = bin30(hv[j]), i2 = bin30(bv[j]);
        float wv = s_dom[i1 * 12 + i2] - dv[j];
        bool on = (wv > 0.0f) && (mp != 0.0f) && (mv[j] != 0.0f) && (c0 + j != p);
        a[j] = f2bf(on ? (__expf(wv) + EPSF) : EPSF);
    }
    return a;
}

// R10 = R9 with the missing La drain fixed. Per-wave schedule:
//   [dom/mask via C] -> fence -> [asm: 8 hv + 12 La, 20 outstanding] -> SB0
//   -> vmcnt(12)+SB0 (hv ready; La = 12 newest still flying) -> stage h to
//   LDS -> __syncthreads (lgkm for staging; does NOT cover asm loads!) ->
//   [asm: 12 Lb] -> SB0 -> vmcnt(12)+SB0 (La ready: Lb are the 12 newest;
//   Lb still flying) -> kb{0,1} compute+MFMA (Lb latency hides here) ->
//   vmcnt(0)+SB0 -> kb{2,3} compute+MFMA -> phases 2-end/3 as before.
// Counted-wait safety: in-order retire; all vmem between batch and wait is
// my asm (SB0 fences + volatile ordering); compiler waits elsewhere only
// over-wait. launch_bounds(256,2): ~170 VGPR live, no spill (a spilled
// pending asm output would corrupt). 2 blocks/CU.
// MFMA order unchanged (kb ascending) -> bitwise-identical output.
__global__ __launch_bounds__(256, 2) void spatial_attn_kernel(
    const float* __restrict__ hidden,   // [B,P,D]
    const float* __restrict__ dist,     // [B,P,P]
    const float* __restrict__ bear,     // [B,P,P]
    const float* __restrict__ head,     // [B,P,P]
    const float* __restrict__ smask,    // [B,P]
    const float* __restrict__ domain,   // [12,12]
    const float* __restrict__ bias,     // [D]
    float* __restrict__ out)            // [B,P,D]
{
    __shared__ __align__(16) short s_w[64 * SW];   // fused [wh|h]
    __shared__ __align__(16) short s_hT[ND * SW];  // s_hT[d][q]=h[q][d]
    __shared__ __align__(16) float s_dom[144];
    __shared__ __align__(16) float s_mask[NP];

    const int blk  = blockIdx.x;
    const int b    = blk >> 1;
    const int half = blk & 1;
    const int tid  = threadIdx.x;
    const int lane = tid & 63;
    const int wave = tid >> 6;          // 0..3
    const int quad = lane >> 4;
    const int l16  = lane & 15;

    const int R0L = wave * 16;          // local row base (of 64)
    const int row = R0L + l16;          // this lane's E row (local)
    const int p   = half * 64 + row;    // this lane's E row (within batch)
    const int c0  = quad * 8;           // in-row column base (floats, 0..24)

    // ---- dom/mask first: compiler inserts its own (tracked) waits here ----
    if (tid < 144) s_dom[tid] = domain[tid];
    if (tid < NP)  s_mask[tid] = smask[b * NP + tid];
    asm volatile("" ::: "memory");      // pin dom/mask ops above the batch

    // ---- byte offsets (32-bit; arrays are 33.5MB / 16.8MB, fits) ----
    const unsigned off_m = ((unsigned)(b * NP * NP) + (unsigned)p * NP
                            + (unsigned)c0) * 4u;
    const unsigned perm  = (unsigned)((tid & 15) * 16 + (tid >> 4));
    unsigned offh[8];
    #pragma unroll
    for (int i = 0; i < 8; ++i)
        offh[i] = (unsigned)b * 32768u + (unsigned)(i * 256) * 16u + perm * 16u;

    // ---- asm batch: 8 hidden f4, then 12 kb{0,1} f4 (20 outstanding) ----
    float4 hv[8];
    GLOADX4(hv[0], offh[0], hidden, "0");
    GLOADX4(hv[1], offh[1], hidden, "0");
    GLOADX4(hv[2], offh[2], hidden, "0");
    GLOADX4(hv[3], offh[3], hidden, "0");
    GLOADX4(hv[4], offh[4], hidden, "0");
    GLOADX4(hv[5], offh[5], hidden, "0");
    GLOADX4(hv[6], offh[6], hidden, "0");
    GLOADX4(hv[7], offh[7], hidden, "0");
    float4 La[12];
    GLOADX4(La[0],  off_m, dist, "0");
    GLOADX4(La[1],  off_m, dist, "16");
    GLOADX4(La[2],  off_m, bear, "0");
    GLOADX4(La[3],  off_m, bear, "16");
    GLOADX4(La[4],  off_m, head, "0");
    GLOADX4(La[5],  off_m, head, "16");
    GLOADX4(La[6],  off_m, dist, "128");
    GLOADX4(La[7],  off_m, dist, "144");
    GLOADX4(La[8],  off_m, bear, "128");
    GLOADX4(La[9],  off_m, bear, "144");
    GLOADX4(La[10], off_m, head, "128");
    GLOADX4(La[11], off_m, head, "144");
    __builtin_amdgcn_sched_barrier(0);

    // hv ready when outstanding <= 12 (La are the 12 newest); rule #18 fence.
    asm volatile("s_waitcnt vmcnt(12)" ::: "memory");
    __builtin_amdgcn_sched_barrier(0);

    // ---- stage h: s_hT (transposed, swizzled perm) + h-cols of fused s_w ----
    #pragma unroll
    for (int i = 0; i < 8; ++i) {
        int idx = i * 256 + (int)perm;
        int q = idx >> 4;            // 0..127
        int d = (idx & 15) * 4;      // 0..60
        short4 s4;
        s4.x = f2bf(hv[i].x); s4.y = f2bf(hv[i].y);
        s4.z = f2bf(hv[i].z); s4.w = f2bf(hv[i].w);
        s_hT[(d + 0) * SW + q] = s4.x;
        s_hT[(d + 1) * SW + q] = s4.y;
        s_hT[(d + 2) * SW + q] = s4.z;
        s_hT[(d + 3) * SW + q] = s4.w;
        int qloc = q - half * 64;
        if (qloc >= 0 && qloc < 64)
            *(short4*)&s_w[qloc * SW + 64 + d] = s4;
    }
    __syncthreads();   // orders LDS staging only; asm loads NOT drained here

    // ---- issue kb{2,3} batch before touching La ----
    float4 Lb[12];
    GLOADX4(Lb[0],  off_m, dist, "256");
    GLOADX4(Lb[1],  off_m, dist, "272");
    GLOADX4(Lb[2],  off_m, bear, "256");
    GLOADX4(Lb[3],  off_m, bear, "272");
    GLOADX4(Lb[4],  off_m, head, "256");
    GLOADX4(Lb[5],  off_m, head, "272");
    GLOADX4(Lb[6],  off_m, dist, "384");
    GLOADX4(Lb[7],  off_m, dist, "400");
    GLOADX4(Lb[8],  off_m, bear, "384");
    GLOADX4(Lb[9],  off_m, bear, "400");
    GLOADX4(Lb[10], off_m, head, "384");
    GLOADX4(Lb[11], off_m, head, "400");
    __builtin_amdgcn_sched_barrier(0);

    // La ready when outstanding <= 12 (Lb are the 12 newest, still flying).
    // THE R5 FIX: this wait was missing; __syncthreads does not drain asm.
    asm volatile("s_waitcnt vmcnt(12)" ::: "memory");
    __builtin_amdgcn_sched_barrier(0);

    const float mp = s_mask[p];

    f32x4 acc[4], accs;
    #pragma unroll
    for (int tj = 0; tj < 4; ++tj) acc[tj] = (f32x4){0.f, 0.f, 0.f, 0.f};
    accs = (f32x4){0.f, 0.f, 0.f, 0.f};
    short8 ones;
    #pragma unroll
    for (int i = 0; i < 8; ++i) ones[i] = (short)0x3F80;  // bf16 1.0

    // ---- kb{0,1} from La (ready; Lb latency hides under this) ----
    #pragma unroll
    for (int k = 0; k < 2; ++k) {
        const int cc = k * 32 + c0;
        float4 m0 = *(const float4*)&s_mask[cc];
        float4 m1 = *(const float4*)&s_mask[cc + 4];
        short8 afr = calc_e8(La[k*6+0], La[k*6+1], La[k*6+2], La[k*6+3],
                             La[k*6+4], La[k*6+5], m0, m1, s_dom, mp, cc, p);
        accs = __builtin_amdgcn_mfma_f32_16x16x32_bf16(afr, ones, accs, 0, 0, 0);
        #pragma unroll
        for (int tj = 0; tj < 4; ++tj) {
            short8 bf = *(const short8*)&s_hT[(tj * 16 + l16) * SW + cc];
            acc[tj] = __builtin_amdgcn_mfma_f32_16x16x32_bf16(afr, bf, acc[tj], 0, 0, 0);
        }
    }

    // ---- drain Lb, then kb{2,3} ----
    asm volatile("s_waitcnt vmcnt(0)" ::: "memory");
    __builtin_amdgcn_sched_barrier(0);
    #pragma unroll
    for (int k = 0; k < 2; ++k) {
        const int cc = (k + 2) * 32 + c0;
        float4 m0 = *(const float4*)&s_mask[cc];
        float4 m1 = *(const float4*)&s_mask[cc + 4];
        short8 afr = calc_e8(Lb[k*6+0], Lb[k*6+1], Lb[k*6+2], Lb[k*6+3],
                             Lb[k*6+4], Lb[k*6+5], m0, m1, s_dom, mp, cc, p);
        accs = __builtin_amdgcn_mfma_f32_16x16x32_bf16(afr, ones, accs, 0, 0, 0);
        #pragma unroll
        for (int tj = 0; tj < 4; ++tj) {
            short8 bf = *(const short8*)&s_hT[(tj * 16 + l16) * SW + cc];
            acc[tj] = __builtin_amdgcn_mfma_f32_16x16x32_bf16(afr, bf, acc[tj], 0, 0, 0);
        }
    }

    // C/D row = quad*4 + r; accs rows match lane-for-lane.
    float inv[4];
    #pragma unroll
    for (int r = 0; r < 4; ++r) inv[r] = 1.0f / (accs[r] + EPSF);

    // ---- wh into fused s_w (wave-local rows; DS in-order per wave) ----
    #pragma unroll
    for (int tj = 0; tj < 4; ++tj)
        #pragma unroll
        for (int r = 0; r < 4; ++r) {
            int rw = R0L + quad * 4 + r;
            s_w[rw * SW + tj * 16 + l16] = f2bf(acc[tj][r] * inv[r]);
        }

    // ---- phase 3: out = tanh(fused @ W^T + b), W-frags from g_wbf (L2) ----
    f32x4 acc2[4];
    #pragma unroll
    for (int tj = 0; tj < 4; ++tj) acc2[tj] = (f32x4){0.f, 0.f, 0.f, 0.f};

    #pragma unroll
    for (int kb = 0; kb < 4; ++kb) {
        const int ko = kb * 32 + c0;
        short8 a = *(const short8*)&s_w[(R0L + l16) * SW + ko];
        #pragma unroll
        for (int tj = 0; tj < 4; ++tj) {
            short8 bf = *(const short8*)&g_wbf[(tj * 16 + l16) * (2 * ND) + ko];
            acc2[tj] = __builtin_amdgcn_mfma_f32_16x16x32_bf16(a, bf, acc2[tj], 0, 0, 0);
        }
    }

    float bvals[4];
    #pragma unroll
    for (int tj = 0; tj < 4; ++tj) bvals[tj] = bias[tj * 16 + l16];

    float* ob = out + ((size_t)b * NP + half * 64) * ND;
    #pragma unroll
    for (int tj = 0; tj < 4; ++tj)
        #pragma unroll
        for (int r = 0; r < 4; ++r) {
            int rw = R0L + quad * 4 + r;
            ob[(size_t)rw * ND + tj * 16 + l16] = fast_tanh(acc2[tj][r] + bvals[tj]);
        }
}

extern "C" void kernel_launch(void* const* d_in, const int* in_sizes, int n_in,
                              void* d_out, int out_size, void* d_ws, size_t ws_size,
                              hipStream_t stream) {
    const float* hidden = (const float*)d_in[0];
    const float* dist   = (const float*)d_in[1];
    const float* bear   = (const float*)d_in[2];
    const float* head   = (const float*)d_in[3];
    const float* smask  = (const float*)d_in[4];
    const float* domain = (const float*)d_in[5];
    const float* W      = (const float*)d_in[6];
    const float* bias   = (const float*)d_in[7];
    float* out = (float*)d_out;

    prep_w<<<dim3(8), dim3(256), 0, stream>>>(W);
    spatial_attn_kernel<<<dim3(NB * 2), dim3(256), 0, stream>>>(
        hidden, dist, bear, head, smask, domain, bias, out);
}